// Round 9
// baseline (47.481 us; speedup 1.0000x reference)
//
#include <hip/hip_runtime.h>
#include <hip/hip_bf16.h>

#define EPS 1e-5f

typedef __bf16 v8bf __attribute__((ext_vector_type(8)));
typedef __bf16 v4bf __attribute__((ext_vector_type(4)));
typedef float  v4f  __attribute__((ext_vector_type(4)));

// ---------------------------------------------------------------------------
// Weight transform: per-tap MFMA B-fragments (unchanged).
// fb1: [ky(5)][nt(2)][lane(64)][8]  k=(dx,ic): dx=k>>2 (0..7), ic=k&3; zero pad
// fb2: [tap(25)][nt(2)][lane(64)][8]  k = ic (0..31)
// fb3: [tap(25)][nt(4)][lane(64)][8]  k = ic (0..31)
// B elem: lane l, reg j -> B[k=(l>>4)*8+j][n=l&15]
// ---------------------------------------------------------------------------
__global__ void k_wtrans(const float* __restrict__ w1, const float* __restrict__ w2,
                         const float* __restrict__ w3,
                         __hip_bfloat16* __restrict__ fb1, __hip_bfloat16* __restrict__ fb2,
                         __hip_bfloat16* __restrict__ fb3)
{
    int idx = blockIdx.x * 256 + threadIdx.x;
    if (idx < 640) {                               // fb1: 5*2*64
        int lane = idx & 63, fi = idx >> 6;        // fi = ky*2 + nt
        int ky = fi >> 1, nt = fi & 1;
        int oc = nt * 16 + (lane & 15), k0 = (lane >> 4) * 8;
        __hip_bfloat16* dst = fb1 + idx * 8;
        #pragma unroll
        for (int j = 0; j < 8; ++j) {
            int k = k0 + j, dx = k >> 2, ic = k & 3;
            float val = (dx < 5 && ic < 3) ? w1[oc * 75 + ic * 25 + ky * 5 + dx] : 0.f;
            dst[j] = __float2bfloat16(val);
        }
    } else if (idx < 640 + 3200) {                 // fb2: 25*2*64
        int k2 = idx - 640;
        int lane = k2 & 63, fi = k2 >> 6;          // fi = tap*2 + nt
        int tap = fi >> 1, nt = fi & 1;
        int oc = nt * 16 + (lane & 15), ic0 = (lane >> 4) * 8;
        __hip_bfloat16* dst = fb2 + k2 * 8;
        #pragma unroll
        for (int j = 0; j < 8; ++j)
            dst[j] = __float2bfloat16(w2[oc * 800 + (ic0 + j) * 25 + tap]);
    } else if (idx < 640 + 3200 + 6400) {          // fb3: 25*4*64
        int k3 = idx - 3840;
        int lane = k3 & 63, fi = k3 >> 6;          // fi = tap*4 + nt
        int tap = fi >> 2, nt = fi & 3;
        int oc = nt * 16 + (lane & 15), ic0 = (lane >> 4) * 8;
        __hip_bfloat16* dst = fb3 + k3 * 8;
        #pragma unroll
        for (int j = 0; j < 8; ++j)
            dst[j] = __float2bfloat16(w3[oc * 800 + (ic0 + j) * 25 + tap]);
    }
}

// ---------------------------------------------------------------------------
// Fused whole-network kernel, 512 threads / 8 waves, 1 image/block.
// R9 = R8 with the LDS pipe load cut ~40%:
//  - conv2: wave = 1 pooled row (8 waves), BOTH nt per wave -> 240 b128 reads
//  - conv3: wave = (mt, nt-pair)                          -> 200 b128 reads
//  - swizzle now blk ^ (col&3) ^ ((col>>2)&3): exact per-phase bank balance
//    (old col&3-only form left cols differing by 4 in identical banks: 4-way)
//  - pad-only zeroing; staging writes full 8-B columns -> init+stage share
//    one barrier phase (4 barriers total)
// LDS pool (36832 B, phase-aliased):
//   xs2 [20][20][32] bf16 swz @ 0      (25600)  conv1-out / conv2-in
//   xs1 [36][39][4]  bf16     @ 25600  (11232)  conv1-in staging
//   xs3 [12][12][32] bf16 swz @ 25600  ( 9216)  conv2-out / conv3-in
//   fin [1024]       f32      @ 0      ( 4096)  conv3-out / fc-in
// ---------------------------------------------------------------------------
#define SWZ(blk, col)      ((blk) ^ ((col) & 3) ^ (((col) >> 2) & 3))
#define XS2(row, col, blk) ((__hip_bfloat16*)(pool + (((((row)*20 + (col))*32) + (SWZ(blk,col)*8))*2)))
#define XS2S(row, col, oc) ((__hip_bfloat16*)(pool + (((((row)*20 + (col))*32) + (SWZ((oc)>>3,col)*8) + ((oc)&7))*2)))
#define XS1(row, col)      ((__hip_bfloat16*)(pool + 25600 + ((((row)*39 + (col))*4)*2)))
#define XS3(row, col, blk) ((__hip_bfloat16*)(pool + 25600 + (((((row)*12 + (col))*32) + (SWZ(blk,col)*8))*2)))
#define XS3S(row, col, oc) ((__hip_bfloat16*)(pool + 25600 + (((((row)*12 + (col))*32) + (SWZ((oc)>>3,col)*8) + ((oc)&7))*2)))

__global__ __launch_bounds__(512, 4) void k_fused(
    const float* __restrict__ x,
    const __hip_bfloat16* __restrict__ fb1,
    const __hip_bfloat16* __restrict__ fb2,
    const __hip_bfloat16* __restrict__ fb3,
    const float* __restrict__ w4,
    const float* __restrict__ g1, const float* __restrict__ b1,
    const float* __restrict__ m1, const float* __restrict__ v1,
    const float* __restrict__ g2, const float* __restrict__ b2,
    const float* __restrict__ m2, const float* __restrict__ v2,
    const float* __restrict__ g3, const float* __restrict__ b3,
    const float* __restrict__ m3, const float* __restrict__ v3,
    const float* __restrict__ g4, const float* __restrict__ b4,
    const float* __restrict__ m4, const float* __restrict__ v4,
    float* __restrict__ out)
{
    __shared__ __align__(16) unsigned char pool[36832];
    __shared__ float sc1[32], bi1[32], sc2[32], bi2[32], sc3[64], bi3[64];
    float* fin = (float*)pool;

    const int img = blockIdx.x, t = threadIdx.x;
    const int lane = t & 63, wave = t >> 6;
    const int lo = lane & 15, hi = lane >> 4;

    // ---- phase 0 (single barrier): BN consts + pad-only zero + stage ----
    if (t < 32) {
        float s = g1[t] * rsqrtf(v1[t] + EPS); sc1[t] = s; bi1[t] = b1[t] - m1[t] * s;
        float u = g2[t] * rsqrtf(v2[t] + EPS); sc2[t] = u; bi2[t] = b2[t] - m2[t] * u;
    }
    if (t < 64) {
        float s = g3[t] * rsqrtf(v3[t] + EPS); sc3[t] = s; bi3[t] = b3[t] - m3[t] * s;
    }
    // zero xs1 pad cols (8B each, 380) then xs2 pad cells (uint4, 576)
    for (int i = t; i < 956; i += 512) {
        if (i < 380) {
            int row, col;
            if (i < 156) { int rr = i / 39; row = rr < 2 ? rr : rr + 32; col = i % 39; }
            else { int j = i - 156; row = 2 + j / 7; int cc = j % 7; col = cc < 2 ? cc : cc + 32; }
            *(uint2*)(pool + 25600 + (row * 39 + col) * 8) = make_uint2(0u, 0u);
        } else {
            int k = i - 380;
            int cell = k >> 2, q = k & 3;
            int row, col;
            if (cell < 80) { int rr = cell / 20; row = rr < 2 ? rr : rr + 16; col = cell % 20; }
            else { int j = cell - 80; row = 2 + (j >> 2); int c2 = j & 3; col = c2 < 2 ? c2 : c2 + 16; }
            *(uint4*)(pool + ((row * 20 + col) * 32 + q * 8) * 2) = make_uint4(0u, 0u, 0u, 0u);
        }
    }
    // stage input: one 8-B column (3 ic + zero) per interior cell
    for (int c = t; c < 1024; c += 512) {
        int y = c >> 5, xx = c & 31;
        int base = img * 3072 + (y << 5) + xx;
        float f0 = x[base], f1 = x[base + 1024], f2 = x[base + 2048];
        __hip_bfloat16 h0 = __float2bfloat16(f0);
        __hip_bfloat16 h1 = __float2bfloat16(f1);
        __hip_bfloat16 h2 = __float2bfloat16(f2);
        uint lo32 = (uint)*(unsigned short*)&h0 | ((uint)*(unsigned short*)&h1 << 16);
        uint hi32 = (uint)*(unsigned short*)&h2;
        *(uint2*)XS1(y + 2, xx + 2) = make_uint2(lo32, hi32);
    }
    __syncthreads();

    // ---- phase 1: conv1 (3->32) -> xs2; wave = 2 consecutive pooled rows ----
    {
        const int y0 = 4 * wave;               // xs1 row window base (8 rows)
        #pragma unroll
        for (int xh = 0; xh < 2; ++xh) {
            const int xx = xh * 16 + lo + hi * 2;
            v8bf av[8];
            #pragma unroll
            for (int r = 0; r < 8; ++r) {
                v4bf lo4 = *(const v4bf*)XS1(y0 + r, xx);
                v4bf hi4 = *(const v4bf*)XS1(y0 + r, xx + 1);
                av[r] = __builtin_shufflevector(lo4, hi4, 0, 1, 2, 3, 4, 5, 6, 7);
            }
            #pragma unroll
            for (int nt = 0; nt < 2; ++nt) {
                v8bf bw[5];
                #pragma unroll
                for (int ky = 0; ky < 5; ++ky)
                    bw[ky] = *(const v8bf*)(fb1 + ((ky * 2 + nt) * 64 + lane) * 8);
                v4f acc[2][2];                 // [pr_i][yb]
                #pragma unroll
                for (int a0 = 0; a0 < 2; ++a0)
                    #pragma unroll
                    for (int a1 = 0; a1 < 2; ++a1)
                        acc[a0][a1] = (v4f){0.f, 0.f, 0.f, 0.f};
                #pragma unroll
                for (int ky = 0; ky < 5; ++ky) {
                    acc[0][0] = __builtin_amdgcn_mfma_f32_16x16x32_bf16(av[ky],     bw[ky], acc[0][0], 0, 0, 0);
                    acc[0][1] = __builtin_amdgcn_mfma_f32_16x16x32_bf16(av[ky + 1], bw[ky], acc[0][1], 0, 0, 0);
                    acc[1][0] = __builtin_amdgcn_mfma_f32_16x16x32_bf16(av[ky + 2], bw[ky], acc[1][0], 0, 0, 0);
                    acc[1][1] = __builtin_amdgcn_mfma_f32_16x16x32_bf16(av[ky + 3], bw[ky], acc[1][1], 0, 0, 0);
                }
                const int oc = nt * 16 + lo;
                const float s = sc1[oc], bb = bi1[oc];
                #pragma unroll
                for (int pri = 0; pri < 2; ++pri) {
                    float u0 = fmaxf(fmaf(acc[pri][0][0], s, bb), 0.f);
                    float u1 = fmaxf(fmaf(acc[pri][0][1], s, bb), 0.f);
                    float u2 = fmaxf(fmaf(acc[pri][0][2], s, bb), 0.f);
                    float u3 = fmaxf(fmaf(acc[pri][0][3], s, bb), 0.f);
                    float q0 = fmaxf(fmaf(acc[pri][1][0], s, bb), 0.f);
                    float q1 = fmaxf(fmaf(acc[pri][1][1], s, bb), 0.f);
                    float q2 = fmaxf(fmaf(acc[pri][1][2], s, bb), 0.f);
                    float q3 = fmaxf(fmaf(acc[pri][1][3], s, bb), 0.f);
                    float p0 = fminf(0.25f * (u0 + u1 + q0 + q1), 1.f);
                    float p1 = fminf(0.25f * (u2 + u3 + q2 + q3), 1.f);
                    const int pr = 2 * wave + pri;
                    const int px = xh * 8 + hi * 2;
                    *XS2S(pr + 2, px + 2, oc) = __float2bfloat16(p0);
                    *XS2S(pr + 2, px + 3, oc) = __float2bfloat16(p1);
                }
            }
        }
    }
    __syncthreads();

    // ---- phase 2: zero xs3 pads + conv2 (32->32) -> xs3; wave = 1 pooled row,
    //      both nt per wave (A-frags read once, reused 2x) ----
    {
        uint* x3u = (uint*)(pool + 25600);     // xs3 as uints, 192/row
        for (int i = t; i < 1280; i += 512) {
            int u;
            if (i < 384)      u = i;                     // rows 0,1
            else if (i < 768) u = 1920 + (i - 384);      // rows 10,11
            else {                                        // rows 2..9 side strips
                int j = i - 768;
                int r = 2 + (j >> 6), c = j & 63;
                u = r * 192 + (c < 32 ? c : 128 + c);    // cols 0-1 / cols 10-11
            }
            x3u[u] = 0u;
        }

        const int rp = wave;                   // pooled row 0..7
        v4f acc[2][2];                          // [yb][nt]
        #pragma unroll
        for (int a0 = 0; a0 < 2; ++a0)
            #pragma unroll
            for (int a1 = 0; a1 < 2; ++a1)
                acc[a0][a1] = (v4f){0.f, 0.f, 0.f, 0.f};

        #pragma unroll
        for (int kx = 0; kx < 5; ++kx) {
            v8bf bf[5][2];
            #pragma unroll
            for (int ky = 0; ky < 5; ++ky)
                #pragma unroll
                for (int nt = 0; nt < 2; ++nt)
                    bf[ky][nt] = *(const v8bf*)(fb2 + ((ky * 5 + kx) * 2 + nt) * 512 + lane * 8);
            v8bf av[6];
            #pragma unroll
            for (int r = 0; r < 6; ++r)
                av[r] = *(const v8bf*)XS2(2 * rp + r, lo + kx, hi);
            #pragma unroll
            for (int ky = 0; ky < 5; ++ky) {
                acc[0][0] = __builtin_amdgcn_mfma_f32_16x16x32_bf16(av[ky],     bf[ky][0], acc[0][0], 0, 0, 0);
                acc[0][1] = __builtin_amdgcn_mfma_f32_16x16x32_bf16(av[ky],     bf[ky][1], acc[0][1], 0, 0, 0);
                acc[1][0] = __builtin_amdgcn_mfma_f32_16x16x32_bf16(av[ky + 1], bf[ky][0], acc[1][0], 0, 0, 0);
                acc[1][1] = __builtin_amdgcn_mfma_f32_16x16x32_bf16(av[ky + 1], bf[ky][1], acc[1][1], 0, 0, 0);
            }
        }

        #pragma unroll
        for (int nt = 0; nt < 2; ++nt) {
            const int oc = nt * 16 + lo;
            const float s = sc2[oc], bb = bi2[oc];
            float u0 = fmaxf(fmaf(acc[0][nt][0], s, bb), 0.f);
            float u1 = fmaxf(fmaf(acc[0][nt][1], s, bb), 0.f);
            float u2 = fmaxf(fmaf(acc[0][nt][2], s, bb), 0.f);
            float u3 = fmaxf(fmaf(acc[0][nt][3], s, bb), 0.f);
            float q0 = fmaxf(fmaf(acc[1][nt][0], s, bb), 0.f);
            float q1 = fmaxf(fmaf(acc[1][nt][1], s, bb), 0.f);
            float q2 = fmaxf(fmaf(acc[1][nt][2], s, bb), 0.f);
            float q3 = fmaxf(fmaf(acc[1][nt][3], s, bb), 0.f);
            float p0 = fminf(0.25f * (u0 + u1 + q0 + q1), 1.f);
            float p1 = fminf(0.25f * (u2 + u3 + q2 + q3), 1.f);
            *XS3S(rp + 2, hi * 2 + 2, oc) = __float2bfloat16(p0);
            *XS3S(rp + 2, hi * 2 + 3, oc) = __float2bfloat16(p1);
        }
    }
    __syncthreads();

    // ---- phase 3: conv3 (32->64) -> fin; wave = (mt 0..3, nt-pair 0..1);
    //      each A-frag read feeds 2 MFMAs ----
    {
        const int mt = wave >> 1, nh = wave & 1;
        const int ya0 = lo >> 3, xa = lo & 7;
        v4f acc[2];                            // per nt in pair
        #pragma unroll
        for (int q = 0; q < 2; ++q) acc[q] = (v4f){0.f, 0.f, 0.f, 0.f};

        #pragma unroll
        for (int ky = 0; ky < 5; ++ky)
            #pragma unroll
            for (int kx = 0; kx < 5; ++kx) {
                const int tap = ky * 5 + kx;
                v8bf av = *(const v8bf*)XS3(2 * mt + ya0 + ky, xa + kx, hi);
                v8bf b0 = *(const v8bf*)(fb3 + (tap * 4 + nh * 2 + 0) * 512 + lane * 8);
                v8bf b1 = *(const v8bf*)(fb3 + (tap * 4 + nh * 2 + 1) * 512 + lane * 8);
                acc[0] = __builtin_amdgcn_mfma_f32_16x16x32_bf16(av, b0, acc[0], 0, 0, 0);
                acc[1] = __builtin_amdgcn_mfma_f32_16x16x32_bf16(av, b1, acc[1], 0, 0, 0);
            }

        const int xb = (hi & 1) * 2;
        #pragma unroll
        for (int ni = 0; ni < 2; ++ni) {
            const int oc = (nh * 2 + ni) * 16 + lo;
            const float s = sc3[oc], bb = bi3[oc];
            float v0 = fmaxf(fmaf(acc[ni][0], s, bb), 0.f);
            float v1 = fmaxf(fmaf(acc[ni][1], s, bb), 0.f);
            float v2 = fmaxf(fmaf(acc[ni][2], s, bb), 0.f);
            float v3 = fmaxf(fmaf(acc[ni][3], s, bb), 0.f);
            float s01 = v0 + v1, s23 = v2 + v3;
            float o01 = __shfl_xor(s01, 32);
            float o23 = __shfl_xor(s23, 32);
            float p0 = fminf(0.25f * (s01 + o01), 1.f);
            float p1 = fminf(0.25f * (s23 + o23), 1.f);
            if (hi < 2) {
                fin[oc * 16 + mt * 4 + xb]     = p0;
                fin[oc * 16 + mt * 4 + xb + 1] = p1;
            }
        }
    }
    __syncthreads();

    // ---- phase 4: FC 1024->10 + BN1d ----
    {
        for (int oc = wave; oc < 10; oc += 8) {
            const float4* wp = (const float4*)(w4 + oc * 1024);
            const float4* fp = (const float4*)fin;
            float acc0 = 0.f, acc1 = 0.f;
            #pragma unroll
            for (int ch = 0; ch < 4; ++ch) {
                float4 a = fp[ch * 64 + lane];
                float4 w = wp[ch * 64 + lane];
                acc0 = fmaf(a.x, w.x, acc0); acc1 = fmaf(a.y, w.y, acc1);
                acc0 = fmaf(a.z, w.z, acc0); acc1 = fmaf(a.w, w.w, acc1);
            }
            float acc = acc0 + acc1;
            acc += __shfl_xor(acc, 1);
            acc += __shfl_xor(acc, 2);
            acc += __shfl_xor(acc, 4);
            acc += __shfl_xor(acc, 8);
            acc += __shfl_xor(acc, 16);
            acc += __shfl_xor(acc, 32);
            if (lane == 0) {
                float s = g4[oc] * rsqrtf(v4[oc] + EPS);
                out[img * 10 + oc] = acc * s + (b4[oc] - m4[oc] * s);
            }
        }
    }
}

extern "C" void kernel_launch(void* const* d_in, const int* in_sizes, int n_in,
                              void* d_out, int out_size, void* d_ws, size_t ws_size,
                              hipStream_t stream) {
    const float* x  = (const float*)d_in[0];
    const float* w1 = (const float*)d_in[1];
    const float* g1 = (const float*)d_in[2];
    const float* b1 = (const float*)d_in[3];
    const float* m1 = (const float*)d_in[4];
    const float* v1 = (const float*)d_in[5];
    const float* w2 = (const float*)d_in[6];
    const float* g2 = (const float*)d_in[7];
    const float* b2 = (const float*)d_in[8];
    const float* m2 = (const float*)d_in[9];
    const float* v2 = (const float*)d_in[10];
    const float* w3 = (const float*)d_in[11];
    const float* g3 = (const float*)d_in[12];
    const float* b3 = (const float*)d_in[13];
    const float* m3 = (const float*)d_in[14];
    const float* v3 = (const float*)d_in[15];
    const float* w4 = (const float*)d_in[16];
    const float* g4 = (const float*)d_in[17];
    const float* b4 = (const float*)d_in[18];
    const float* m4 = (const float*)d_in[19];
    const float* v4 = (const float*)d_in[20];
    float* out = (float*)d_out;

    char* base = (char*)d_ws;
    __hip_bfloat16* fb1 = (__hip_bfloat16*)base;             // 10.24 KB (pad to 16K)
    __hip_bfloat16* fb2 = (__hip_bfloat16*)(base + 16384);   // 51.2 KB
    __hip_bfloat16* fb3 = (__hip_bfloat16*)(base + 67584);   // 102.4 KB

    k_wtrans<<<40, 256, 0, stream>>>(w1, w2, w3, fb1, fb2, fb3);
    k_fused<<<1024, 512, 0, stream>>>(x, fb1, fb2, fb3, w4,
                                      g1, b1, m1, v1, g2, b2, m2, v2,
                                      g3, b3, m3, v3, g4, b4, m4, v4, out);
}

// Round 10
// 39.363 us; speedup vs baseline: 1.2062x; 1.2062x over previous
//
#include <hip/hip_runtime.h>
#include <hip/hip_bf16.h>

#define EPS 1e-5f

typedef __bf16 v8bf __attribute__((ext_vector_type(8)));
typedef __bf16 v4bf __attribute__((ext_vector_type(4)));
typedef float  v4f  __attribute__((ext_vector_type(4)));

// ---------------------------------------------------------------------------
// Weight transform: per-tap MFMA B-fragments (unchanged).
// fb1: [ky(5)][nt(2)][lane(64)][8]  k=(dx,ic): dx=k>>2 (0..7), ic=k&3; zero pad
// fb2: [tap(25)][nt(2)][lane(64)][8]  k = ic (0..31)
// fb3: [tap(25)][nt(4)][lane(64)][8]  k = ic (0..31)
// B elem: lane l, reg j -> B[k=(l>>4)*8+j][n=l&15]
// ---------------------------------------------------------------------------
__global__ void k_wtrans(const float* __restrict__ w1, const float* __restrict__ w2,
                         const float* __restrict__ w3,
                         __hip_bfloat16* __restrict__ fb1, __hip_bfloat16* __restrict__ fb2,
                         __hip_bfloat16* __restrict__ fb3)
{
    int idx = blockIdx.x * 256 + threadIdx.x;
    if (idx < 640) {                               // fb1: 5*2*64
        int lane = idx & 63, fi = idx >> 6;        // fi = ky*2 + nt
        int ky = fi >> 1, nt = fi & 1;
        int oc = nt * 16 + (lane & 15), k0 = (lane >> 4) * 8;
        __hip_bfloat16* dst = fb1 + idx * 8;
        #pragma unroll
        for (int j = 0; j < 8; ++j) {
            int k = k0 + j, dx = k >> 2, ic = k & 3;
            float val = (dx < 5 && ic < 3) ? w1[oc * 75 + ic * 25 + ky * 5 + dx] : 0.f;
            dst[j] = __float2bfloat16(val);
        }
    } else if (idx < 640 + 3200) {                 // fb2: 25*2*64
        int k2 = idx - 640;
        int lane = k2 & 63, fi = k2 >> 6;          // fi = tap*2 + nt
        int tap = fi >> 1, nt = fi & 1;
        int oc = nt * 16 + (lane & 15), ic0 = (lane >> 4) * 8;
        __hip_bfloat16* dst = fb2 + k2 * 8;
        #pragma unroll
        for (int j = 0; j < 8; ++j)
            dst[j] = __float2bfloat16(w2[oc * 800 + (ic0 + j) * 25 + tap]);
    } else if (idx < 640 + 3200 + 6400) {          // fb3: 25*4*64
        int k3 = idx - 3840;
        int lane = k3 & 63, fi = k3 >> 6;          // fi = tap*4 + nt
        int tap = fi >> 2, nt = fi & 3;
        int oc = nt * 16 + (lane & 15), ic0 = (lane >> 4) * 8;
        __hip_bfloat16* dst = fb3 + k3 * 8;
        #pragma unroll
        for (int j = 0; j < 8; ++j)
            dst[j] = __float2bfloat16(w3[oc * 800 + (ic0 + j) * 25 + tap]);
    }
}

// ---------------------------------------------------------------------------
// Fused whole-network kernel, R10 = R8 structure x 2 IMAGES PER BLOCK.
// Rationale: every B-frag load feeds 2x MFMAs; the two images' instruction
// streams are independent -> in-wave ILP covers L2/LDS latency (the one
// hypothesis not yet falsified by R5-R9).
// Grid 512 blocks x 512 thr; LDS 73664+1KB -> 2 blocks/CU (16 waves/CU =
// 4 waves/EU; launch_bounds(512,4) -> VGPR cap 128, matching the LDS cap).
// LDS pool (73664 B, phase-aliased):
//   xs2[im] [20][20][32] bf16 swz @ im*25600        conv1-out / conv2-in
//   xs1[im] [36][39][4]  bf16     @ 51200+im*11232  conv1-in staging
//   xs3[im] [12][12][32] bf16 swz @ 51200+im*9216   conv2-out / conv3-in
//   fin[im] [1024]       f32      @ im*4096         conv3-out / fc-in
// Swizzle (R8 form): 16-B ic-block index ^= (col&3).
// ---------------------------------------------------------------------------
#define SWZ(blk, col)          ((blk) ^ ((col) & 3))
#define XS2(im, row, col, blk) ((__hip_bfloat16*)(pool + (im)*25600 + (((((row)*20 + (col))*32) + (SWZ(blk,col)*8))*2)))
#define XS2S(im, row, col, oc) ((__hip_bfloat16*)(pool + (im)*25600 + (((((row)*20 + (col))*32) + (SWZ((oc)>>3,col)*8) + ((oc)&7))*2)))
#define XS1(im, row, col)      ((__hip_bfloat16*)(pool + 51200 + (im)*11232 + ((((row)*39 + (col))*4)*2)))
#define XS3(im, row, col, blk) ((__hip_bfloat16*)(pool + 51200 + (im)*9216 + (((((row)*12 + (col))*32) + (SWZ(blk,col)*8))*2)))
#define XS3S(im, row, col, oc) ((__hip_bfloat16*)(pool + 51200 + (im)*9216 + (((((row)*12 + (col))*32) + (SWZ((oc)>>3,col)*8) + ((oc)&7))*2)))

__global__ __launch_bounds__(512, 4) void k_fused(
    const float* __restrict__ x,
    const __hip_bfloat16* __restrict__ fb1,
    const __hip_bfloat16* __restrict__ fb2,
    const __hip_bfloat16* __restrict__ fb3,
    const float* __restrict__ w4,
    const float* __restrict__ g1, const float* __restrict__ b1,
    const float* __restrict__ m1, const float* __restrict__ v1,
    const float* __restrict__ g2, const float* __restrict__ b2,
    const float* __restrict__ m2, const float* __restrict__ v2,
    const float* __restrict__ g3, const float* __restrict__ b3,
    const float* __restrict__ m3, const float* __restrict__ v3,
    const float* __restrict__ g4, const float* __restrict__ b4,
    const float* __restrict__ m4, const float* __restrict__ v4,
    float* __restrict__ out)
{
    __shared__ __align__(16) unsigned char pool[73664];
    __shared__ float sc1[32], bi1[32], sc2[32], bi2[32], sc3[64], bi3[64];

    const int img0 = blockIdx.x * 2, t = threadIdx.x;
    const int lane = t & 63, wave = t >> 6;
    const int lo = lane & 15, hi = lane >> 4;

    // ---- init: zero whole pool (4604 uint4), BN affine consts ----
    for (int i = t; i < 4604; i += 512) ((uint4*)pool)[i] = make_uint4(0, 0, 0, 0);
    if (t < 32) {
        float s = g1[t] * rsqrtf(v1[t] + EPS); sc1[t] = s; bi1[t] = b1[t] - m1[t] * s;
        float u = g2[t] * rsqrtf(v2[t] + EPS); sc2[t] = u; bi2[t] = b2[t] - m2[t] * u;
    }
    if (t < 64) {
        float s = g3[t] * rsqrtf(v3[t] + EPS); sc3[t] = s; bi3[t] = b3[t] - m3[t] * s;
    }
    __syncthreads();

    // ---- phase 0: stage both images -> xs1 (bf16 [y][x][ic] interior) ----
    #pragma unroll
    for (int im = 0; im < 2; ++im) {
        for (int i = t; i < 768; i += 512) {
            float4 val = *(const float4*)(x + (size_t)(img0 + im) * 3072 + i * 4);
            int ic = i >> 8, rem = i & 255;
            int y = rem >> 3, xx = (rem & 7) * 4;
            XS1(im, y + 2, xx + 2)[ic] = __float2bfloat16(val.x);
            XS1(im, y + 2, xx + 3)[ic] = __float2bfloat16(val.y);
            XS1(im, y + 2, xx + 4)[ic] = __float2bfloat16(val.z);
            XS1(im, y + 2, xx + 5)[ic] = __float2bfloat16(val.w);
        }
    }
    __syncthreads();

    // ---- phase 1: conv1 (3->32) x2 -> xs2; wave = 2 consecutive pooled rows,
    //      B-frags bw[5][2] hoisted and reused across both images ----
    {
        v8bf bw[5][2];
        #pragma unroll
        for (int ky = 0; ky < 5; ++ky)
            #pragma unroll
            for (int nt = 0; nt < 2; ++nt)
                bw[ky][nt] = *(const v8bf*)(fb1 + ((ky * 2 + nt) * 64 + lane) * 8);

        const int y0 = 4 * wave;               // xs1 row window base (8 rows)
        #pragma unroll
        for (int im = 0; im < 2; ++im) {
            #pragma unroll
            for (int xh = 0; xh < 2; ++xh) {
                const int xx = xh * 16 + lo + hi * 2;
                v8bf av[8];
                #pragma unroll
                for (int r = 0; r < 8; ++r) {
                    v4bf lo4 = *(const v4bf*)XS1(im, y0 + r, xx);
                    v4bf hi4 = *(const v4bf*)XS1(im, y0 + r, xx + 1);
                    av[r] = __builtin_shufflevector(lo4, hi4, 0, 1, 2, 3, 4, 5, 6, 7);
                }
                #pragma unroll
                for (int nt = 0; nt < 2; ++nt) {
                    v4f acc[2][2];             // [pr_i][yb]
                    #pragma unroll
                    for (int a0 = 0; a0 < 2; ++a0)
                        #pragma unroll
                        for (int a1 = 0; a1 < 2; ++a1)
                            acc[a0][a1] = (v4f){0.f, 0.f, 0.f, 0.f};
                    #pragma unroll
                    for (int ky = 0; ky < 5; ++ky) {
                        acc[0][0] = __builtin_amdgcn_mfma_f32_16x16x32_bf16(av[ky],     bw[ky][nt], acc[0][0], 0, 0, 0);
                        acc[0][1] = __builtin_amdgcn_mfma_f32_16x16x32_bf16(av[ky + 1], bw[ky][nt], acc[0][1], 0, 0, 0);
                        acc[1][0] = __builtin_amdgcn_mfma_f32_16x16x32_bf16(av[ky + 2], bw[ky][nt], acc[1][0], 0, 0, 0);
                        acc[1][1] = __builtin_amdgcn_mfma_f32_16x16x32_bf16(av[ky + 3], bw[ky][nt], acc[1][1], 0, 0, 0);
                    }
                    const int oc = nt * 16 + lo;
                    const float s = sc1[oc], bb = bi1[oc];
                    #pragma unroll
                    for (int pri = 0; pri < 2; ++pri) {
                        float u0 = fmaxf(fmaf(acc[pri][0][0], s, bb), 0.f);
                        float u1 = fmaxf(fmaf(acc[pri][0][1], s, bb), 0.f);
                        float u2 = fmaxf(fmaf(acc[pri][0][2], s, bb), 0.f);
                        float u3 = fmaxf(fmaf(acc[pri][0][3], s, bb), 0.f);
                        float q0 = fmaxf(fmaf(acc[pri][1][0], s, bb), 0.f);
                        float q1 = fmaxf(fmaf(acc[pri][1][1], s, bb), 0.f);
                        float q2 = fmaxf(fmaf(acc[pri][1][2], s, bb), 0.f);
                        float q3 = fmaxf(fmaf(acc[pri][1][3], s, bb), 0.f);
                        float p0 = fminf(0.25f * (u0 + u1 + q0 + q1), 1.f);
                        float p1 = fminf(0.25f * (u2 + u3 + q2 + q3), 1.f);
                        const int pr = 2 * wave + pri;
                        const int px = xh * 8 + hi * 2;
                        *XS2S(im, pr + 2, px + 2, oc) = __float2bfloat16(p0);
                        *XS2S(im, pr + 2, px + 3, oc) = __float2bfloat16(p1);
                    }
                }
            }
        }
    }
    __syncthreads();

    // ---- phase 2: zero xs3 pad cells (both im) + conv2 (32->32) x2 -> xs3;
    //      wave = (wgrp 0..3, nt 0..1); bf[5] shared across both images ----
    {
        for (int i = t; i < 2560; i += 512) {
            int im = i >= 1280, j = i - im * 1280;
            uint* x3u = (uint*)(pool + 51200 + im * 9216);
            int u;
            if (j < 384)      u = j;                     // rows 0,1
            else if (j < 768) u = 1920 + (j - 384);      // rows 10,11
            else {                                        // rows 2..9 side strips
                int k = j - 768;
                int r = 2 + (k >> 6), c = k & 63;
                u = r * 192 + (c < 32 ? c : 128 + c);    // cols 0-1 / cols 10-11
            }
            x3u[u] = 0u;
        }

        const int nt = wave & 1, wgrp = wave >> 1;
        v4f acc2[2][2][2];                      // [im][pri][yb]
        #pragma unroll
        for (int a0 = 0; a0 < 2; ++a0)
            #pragma unroll
            for (int a1 = 0; a1 < 2; ++a1)
                #pragma unroll
                for (int a2 = 0; a2 < 2; ++a2)
                    acc2[a0][a1][a2] = (v4f){0.f, 0.f, 0.f, 0.f};

        #pragma unroll
        for (int kx = 0; kx < 5; ++kx) {
            v8bf bf[5];
            #pragma unroll
            for (int ky = 0; ky < 5; ++ky)
                bf[ky] = *(const v8bf*)(fb2 + ((ky * 5 + kx) * 2 + nt) * 512 + lane * 8);
            #pragma unroll
            for (int im = 0; im < 2; ++im) {
                v8bf av[8];
                #pragma unroll
                for (int r = 0; r < 8; ++r)
                    av[r] = *(const v8bf*)XS2(im, 4 * wgrp + r, lo + kx, hi);
                #pragma unroll
                for (int ky = 0; ky < 5; ++ky) {
                    acc2[im][0][0] = __builtin_amdgcn_mfma_f32_16x16x32_bf16(av[ky],     bf[ky], acc2[im][0][0], 0, 0, 0);
                    acc2[im][0][1] = __builtin_amdgcn_mfma_f32_16x16x32_bf16(av[ky + 1], bf[ky], acc2[im][0][1], 0, 0, 0);
                    acc2[im][1][0] = __builtin_amdgcn_mfma_f32_16x16x32_bf16(av[ky + 2], bf[ky], acc2[im][1][0], 0, 0, 0);
                    acc2[im][1][1] = __builtin_amdgcn_mfma_f32_16x16x32_bf16(av[ky + 3], bf[ky], acc2[im][1][1], 0, 0, 0);
                }
            }
        }

        const int oc = nt * 16 + lo;
        const float s = sc2[oc], bb = bi2[oc];
        #pragma unroll
        for (int im = 0; im < 2; ++im)
            #pragma unroll
            for (int pri = 0; pri < 2; ++pri) {
                const int rp = wgrp * 2 + pri;
                float u0 = fmaxf(fmaf(acc2[im][pri][0][0], s, bb), 0.f);
                float u1 = fmaxf(fmaf(acc2[im][pri][0][1], s, bb), 0.f);
                float u2 = fmaxf(fmaf(acc2[im][pri][0][2], s, bb), 0.f);
                float u3 = fmaxf(fmaf(acc2[im][pri][0][3], s, bb), 0.f);
                float q0 = fmaxf(fmaf(acc2[im][pri][1][0], s, bb), 0.f);
                float q1 = fmaxf(fmaf(acc2[im][pri][1][1], s, bb), 0.f);
                float q2 = fmaxf(fmaf(acc2[im][pri][1][2], s, bb), 0.f);
                float q3 = fmaxf(fmaf(acc2[im][pri][1][3], s, bb), 0.f);
                float p0 = fminf(0.25f * (u0 + u1 + q0 + q1), 1.f);
                float p1 = fminf(0.25f * (u2 + u3 + q2 + q3), 1.f);
                *XS3S(im, rp + 2, hi * 2 + 2, oc) = __float2bfloat16(p0);
                *XS3S(im, rp + 2, hi * 2 + 3, oc) = __float2bfloat16(p1);
            }
    }
    __syncthreads();

    // ---- phase 3: conv3 (32->64) x2 -> fin; wave = (mt 0..3, nt-pair 0..1);
    //      b0/b1 shared across both images (4 MFMAs per 2 L2 loads) ----
    {
        const int mt = wave >> 1, nh = wave & 1;
        const int ya0 = lo >> 3, xa = lo & 7;
        v4f acc3[2][2];                        // [im][ni]
        #pragma unroll
        for (int a0 = 0; a0 < 2; ++a0)
            #pragma unroll
            for (int a1 = 0; a1 < 2; ++a1)
                acc3[a0][a1] = (v4f){0.f, 0.f, 0.f, 0.f};

        #pragma unroll
        for (int ky = 0; ky < 5; ++ky)
            #pragma unroll
            for (int kx = 0; kx < 5; ++kx) {
                const int tap = ky * 5 + kx;
                v8bf b0 = *(const v8bf*)(fb3 + (tap * 4 + nh * 2 + 0) * 512 + lane * 8);
                v8bf b1 = *(const v8bf*)(fb3 + (tap * 4 + nh * 2 + 1) * 512 + lane * 8);
                #pragma unroll
                for (int im = 0; im < 2; ++im) {
                    v8bf av = *(const v8bf*)XS3(im, 2 * mt + ya0 + ky, xa + kx, hi);
                    acc3[im][0] = __builtin_amdgcn_mfma_f32_16x16x32_bf16(av, b0, acc3[im][0], 0, 0, 0);
                    acc3[im][1] = __builtin_amdgcn_mfma_f32_16x16x32_bf16(av, b1, acc3[im][1], 0, 0, 0);
                }
            }

        const int xb = (hi & 1) * 2;
        #pragma unroll
        for (int im = 0; im < 2; ++im) {
            float* fin = (float*)(pool + im * 4096);
            #pragma unroll
            for (int ni = 0; ni < 2; ++ni) {
                const int oc = (nh * 2 + ni) * 16 + lo;
                const float s = sc3[oc], bb = bi3[oc];
                float v0 = fmaxf(fmaf(acc3[im][ni][0], s, bb), 0.f);
                float v1 = fmaxf(fmaf(acc3[im][ni][1], s, bb), 0.f);
                float v2 = fmaxf(fmaf(acc3[im][ni][2], s, bb), 0.f);
                float v3 = fmaxf(fmaf(acc3[im][ni][3], s, bb), 0.f);
                float s01 = v0 + v1, s23 = v2 + v3;
                float o01 = __shfl_xor(s01, 32);
                float o23 = __shfl_xor(s23, 32);
                float p0 = fminf(0.25f * (s01 + o01), 1.f);
                float p1 = fminf(0.25f * (s23 + o23), 1.f);
                if (hi < 2) {
                    fin[oc * 16 + mt * 4 + xb]     = p0;
                    fin[oc * 16 + mt * 4 + xb + 1] = p1;
                }
            }
        }
    }
    __syncthreads();

    // ---- phase 4: FC 1024->10 + BN1d, 20 (im,oc) tasks over 8 waves ----
    {
        for (int task = wave; task < 20; task += 8) {
            const int im = task >= 10, oc = task - im * 10;
            const float4* wp = (const float4*)(w4 + oc * 1024);
            const float4* fp = (const float4*)(pool + im * 4096);
            float acc0 = 0.f, acc1 = 0.f;
            #pragma unroll
            for (int ch = 0; ch < 4; ++ch) {
                float4 a = fp[ch * 64 + lane];
                float4 w = wp[ch * 64 + lane];
                acc0 = fmaf(a.x, w.x, acc0); acc1 = fmaf(a.y, w.y, acc1);
                acc0 = fmaf(a.z, w.z, acc0); acc1 = fmaf(a.w, w.w, acc1);
            }
            float acc = acc0 + acc1;
            acc += __shfl_xor(acc, 1);
            acc += __shfl_xor(acc, 2);
            acc += __shfl_xor(acc, 4);
            acc += __shfl_xor(acc, 8);
            acc += __shfl_xor(acc, 16);
            acc += __shfl_xor(acc, 32);
            if (lane == 0) {
                float s = g4[oc] * rsqrtf(v4[oc] + EPS);
                out[(img0 + im) * 10 + oc] = acc * s + (b4[oc] - m4[oc] * s);
            }
        }
    }
}

extern "C" void kernel_launch(void* const* d_in, const int* in_sizes, int n_in,
                              void* d_out, int out_size, void* d_ws, size_t ws_size,
                              hipStream_t stream) {
    const float* x  = (const float*)d_in[0];
    const float* w1 = (const float*)d_in[1];
    const float* g1 = (const float*)d_in[2];
    const float* b1 = (const float*)d_in[3];
    const float* m1 = (const float*)d_in[4];
    const float* v1 = (const float*)d_in[5];
    const float* w2 = (const float*)d_in[6];
    const float* g2 = (const float*)d_in[7];
    const float* b2 = (const float*)d_in[8];
    const float* m2 = (const float*)d_in[9];
    const float* v2 = (const float*)d_in[10];
    const float* w3 = (const float*)d_in[11];
    const float* g3 = (const float*)d_in[12];
    const float* b3 = (const float*)d_in[13];
    const float* m3 = (const float*)d_in[14];
    const float* v3 = (const float*)d_in[15];
    const float* w4 = (const float*)d_in[16];
    const float* g4 = (const float*)d_in[17];
    const float* b4 = (const float*)d_in[18];
    const float* m4 = (const float*)d_in[19];
    const float* v4 = (const float*)d_in[20];
    float* out = (float*)d_out;

    char* base = (char*)d_ws;
    __hip_bfloat16* fb1 = (__hip_bfloat16*)base;             // 10.24 KB (pad to 16K)
    __hip_bfloat16* fb2 = (__hip_bfloat16*)(base + 16384);   // 51.2 KB
    __hip_bfloat16* fb3 = (__hip_bfloat16*)(base + 67584);   // 102.4 KB

    k_wtrans<<<40, 256, 0, stream>>>(w1, w2, w3, fb1, fb2, fb3);
    k_fused<<<512, 512, 0, stream>>>(x, fb1, fb2, fb3, w4,
                                     g1, b1, m1, v1, g2, b2, m2, v2,
                                     g3, b3, m3, v3, g4, b4, m4, v4, out);
}